// Round 10
// baseline (728.548 us; speedup 1.0000x reference)
//
#include <hip/hip_runtime.h>
#include <hip/hip_bf16.h>
#include <math.h>

// DeepSeekMoE: T=4096, H=1024, F=4096, E=8, top-2 sigmoid routing.
// Round 10: fused weight-convert, CORRECT BY CONSTRUCTION. r8/r9's hand
// vmcnt(4) counting was unsound (scheduler reorders VMEM issue order). Now:
// NO global_load_lds, no hand vmcnt. Both operands reg-staged (A dist-1,
// B fp32 dist-2 named brE/brO) -> ds_write; compiler inserts exact per-reg
// waits; barrier = lgkmcnt(0) + raw s_barrier (B prefetch rides across).
// Flat balanced grids + XCD swizzle kept from r7.

#define T_TOK 4096
#define H_DIM 1024
#define F_DIM 4096
#define NEXP  8
#define RT    (2 * T_TOK)
#define RPAD  512

// worst-case flat grid sizes (fixed for graph capture)
#define G1_TILES 56    // 16 shared + max 40 expert M-tiles (BM=256)
#define G2_TILES 104   // 32 shared + max 72 expert M-tiles (BM=128)
#define G1_GRID  (G1_TILES * 16)   // NB1 = F/256 = 16
#define G2_GRID  (G2_TILES * 8)    // NB2 = H/128 = 8

typedef __bf16 bf16_t;
typedef __bf16 bf16x8 __attribute__((ext_vector_type(8)));
typedef float  f32x4  __attribute__((ext_vector_type(4)));
typedef unsigned short u16x8 __attribute__((ext_vector_type(8)));

#define CFENCE() asm volatile("" ::: "memory")
#define RAWBAR() do { CFENCE(); __builtin_amdgcn_s_barrier(); CFENCE(); } while (0)
#define LGKM0()  asm volatile("s_waitcnt lgkmcnt(0)" ::: "memory")

__device__ __forceinline__ unsigned short f2bf(float f) {
  union { bf16_t b; unsigned short u; } cv;
  cv.b = (bf16_t)f;   // RNE, identical to the old convert pass
  return cv.u;
}

__device__ __forceinline__ float gelu_exact(float v) {
  return 0.5f * v * (1.0f + erff(v * 0.70710678118654752f));
}

// bijective XCD swizzle (m204)
__device__ __forceinline__ int xcd_swizzle(int orig, int nwg) {
  const int q = nwg >> 3, r = nwg & 7;
  const int xcd = orig & 7, idx = orig >> 3;
  return (xcd < r ? xcd * (q + 1) : r * (q + 1) + (xcd - r) * q) + idx;
}

// ---------------------------------------------------------------- small kernels

__global__ void zero_kernel(int* p) {
  if (threadIdx.x < 16) p[threadIdx.x] = 0;
}

// one wave per token: 8 gate scores -> sigmoid -> top2; also emits x in bf16
__global__ void gate_kernel(const float* __restrict__ x, const float* __restrict__ gw,
                            const float* __restrict__ gb, const float* __restrict__ rb,
                            unsigned short* __restrict__ x_bf,
                            int* __restrict__ tok_e, float* __restrict__ tok_w,
                            int* __restrict__ counts) {
  int tkn = blockIdx.x;
  int lane = threadIdx.x;
  float acc[NEXP];
  #pragma unroll
  for (int e = 0; e < NEXP; ++e) acc[e] = 0.f;
  const float* xr = x + (long)tkn * H_DIM;
  unsigned short* xbr = x_bf + (long)tkn * H_DIM;
  for (int k = lane; k < H_DIM; k += 64) {
    float xv = xr[k];
    xbr[k] = f2bf(xv);
    #pragma unroll
    for (int e = 0; e < NEXP; ++e) acc[e] += xv * gw[e * H_DIM + k];
  }
  #pragma unroll
  for (int off = 32; off > 0; off >>= 1) {
    #pragma unroll
    for (int e = 0; e < NEXP; ++e) acc[e] += __shfl_xor(acc[e], off, 64);
  }
  if (lane == 0) {
    float s[NEXP];
    #pragma unroll
    for (int e = 0; e < NEXP; ++e)
      s[e] = 1.f / (1.f + expf(-(acc[e] + gb[e] + rb[e])));
    int e0 = 0;
    #pragma unroll
    for (int e = 1; e < NEXP; ++e) if (s[e] > s[e0]) e0 = e;
    int e1 = (e0 == 0) ? 1 : 0;
    #pragma unroll
    for (int e = 0; e < NEXP; ++e) if (e != e0 && e != e1 && s[e] > s[e1]) e1 = e;
    tok_e[2 * tkn] = e0;  tok_e[2 * tkn + 1] = e1;
    tok_w[2 * tkn] = s[e0]; tok_w[2 * tkn + 1] = s[e1];
    atomicAdd(&counts[e0], 1);
    atomicAdd(&counts[e1], 1);
  }
}

// row offsets + per-group M-tile offset tables for both GEMMs.
__global__ void scan_kernel(const int* __restrict__ counts, int* __restrict__ offs,
                            int* __restrict__ t1, int* __restrict__ t2) {
  if (threadIdx.x == 0) {
    int o = 0, a1 = 0, a2 = 0;
    for (int e = 0; e < NEXP; ++e) {
      offs[e] = o;
      t1[e] = a1; t2[e] = a2;
      a1 += (counts[e] + 255) >> 8;
      a2 += (counts[e] + 127) >> 7;
      o += counts[e];
    }
    t1[8] = a1; t2[8] = a2;
    t1[9] = a1 + (T_TOK >> 8);
    t2[9] = a2 + (T_TOK >> 7);
  }
}

__global__ void build_kernel(const int* __restrict__ tok_e, const float* __restrict__ tok_w,
                             const int* __restrict__ offs, int* __restrict__ cursor,
                             int* __restrict__ btok, float* __restrict__ bw,
                             int* __restrict__ tokpos) {
  int tkn = blockIdx.x * blockDim.x + threadIdx.x;
  if (tkn >= T_TOK) return;
  #pragma unroll
  for (int k = 0; k < 2; ++k) {
    int e = tok_e[2 * tkn + k];
    int p = offs[e] + atomicAdd(&cursor[e], 1);
    btok[p] = tkn;
    bw[p] = tok_w[2 * tkn + k];
    tokpos[2 * tkn + k] = p;
  }
}

// copy x_bf row -> gathered bf16 row, bucket order (16B/thread)
__global__ void gather_kernel(const unsigned short* __restrict__ x_bf,
                              const int* __restrict__ btok,
                              unsigned short* __restrict__ gx) {
  int p = blockIdx.x, tid = threadIdx.x;   // 128 threads * 8 bf16
  int tkn = btok[p];
  u16x8 v = *(const u16x8*)(x_bf + (long)tkn * H_DIM + tid * 8);
  *(u16x8*)(gx + (long)p * H_DIM + tid * 8) = v;
}

__global__ void combine_kernel(float* __restrict__ out, const float* __restrict__ rout,
                               const int* __restrict__ tokpos) {
  int tkn = blockIdx.x, c = threadIdx.x;
  int p0 = tokpos[2 * tkn], p1 = tokpos[2 * tkn + 1];
  f32x4* o = (f32x4*)out + (long)tkn * 256;
  const f32x4* a = (const f32x4*)rout + (long)p0 * 256;
  const f32x4* b = (const f32x4*)rout + (long)p1 * 256;
  o[c] = o[c] + a[c] + b[c];
}

// ---------------------------------------------------------------- grouped GEMM1
// Flat grid. 256x256, BK=32, 8 waves, 2-phase, ALL-REG-STAGED:
// A bf16 -> regs (dist-1) -> ds_write; B fp32 -> regs (dist-2, brE/brO) ->
// cvt -> ds_write. Barrier = lgkmcnt(0) + raw s_barrier (no vmcnt drain).
// C = gelu(A @ B^T + bias) bf16. K=1024, N=4096, NB=16.
__global__ __launch_bounds__(512)
void moe_gemm1(const unsigned short* __restrict__ Ash, const unsigned short* __restrict__ Art,
               const float* __restrict__ Wsh, const float* __restrict__ Wrt,
               const float* __restrict__ bsh, const float* __restrict__ brt,
               unsigned short* __restrict__ Csh, unsigned short* __restrict__ Crt,
               const int* __restrict__ cnts, const int* __restrict__ offs,
               const int* __restrict__ tt) {
  __shared__ __align__(16) unsigned short lds[2][2][256][32];   // 64 KB
  const int wid = xcd_swizzle(blockIdx.x, G1_GRID);
  const int mt = wid >> 4, nb = wid & 15;
  if (mt >= tt[9]) return;
  int z = 0;
  while (mt >= tt[z + 1]) ++z;
  const int mlocal = mt - tt[z];

  const unsigned short* A;
  const float* Bp;
  const float* bias;
  unsigned short* C;
  int mcnt;
  if (z == NEXP) {
    A = Ash; Bp = Wsh; bias = bsh; C = Csh; mcnt = T_TOK;
  } else {
    const int off = offs[z];
    mcnt = cnts[z];
    A = Art + (long)off * H_DIM;
    Bp = Wrt + (long)z * F_DIM * H_DIM;
    bias = brt + z * F_DIM;
    C = Crt + (long)off * F_DIM;
  }

  const int t = threadIdx.x;
  f32x4 acc[8][4] = {};
  const int nk = H_DIM >> 5;           // 32 K-steps (even)

  // per-thread staging: 2 row-blocks, row = i*128 + (t>>2), col chunk (t&3)*8
  const int srow = t >> 2;
  const int scol = (t & 3) * 8;

  u16x8 ar[2];                         // A dist-1 regs (16 bf16)
  f32x4 brE[4], brO[4];                // B dist-2 named regs (16 f32 each)

  auto issueA = [&](int kt) {
    #pragma unroll
    for (int i = 0; i < 2; ++i)
      ar[i] = *(const u16x8*)(A + (long)(mlocal * 256 + i * 128 + srow) * H_DIM + kt * 32 + scol);
  };
  auto writeA = [&](int buf) {
    #pragma unroll
    for (int i = 0; i < 2; ++i)
      *(u16x8*)&lds[buf][0][i * 128 + srow][scol] = ar[i];
  };
  auto issueB = [&](int kt, f32x4* br) {
    #pragma unroll
    for (int i = 0; i < 2; ++i) {
      const float* g = Bp + (long)(nb * 256 + i * 128 + srow) * H_DIM + kt * 32 + scol;
      br[i * 2]     = *(const f32x4*)g;
      br[i * 2 + 1] = *(const f32x4*)(g + 4);
    }
  };
  auto writeB = [&](const f32x4* br, int buf) {
    #pragma unroll
    for (int i = 0; i < 2; ++i) {
      u16x8 o;
      #pragma unroll
      for (int j = 0; j < 4; ++j) {
        o[j]     = f2bf(br[i * 2][j]);
        o[4 + j] = f2bf(br[i * 2 + 1][j]);
      }
      *(u16x8*)&lds[buf][1][i * 128 + srow][scol] = o;
    }
  };

  const int l = t & 63;
  const int w = t >> 6;                       // 8 waves: 2M x 4N
  const int wr = (w >> 2) * 128, wc = (w & 3) * 64;
  const int lr = l & 15, lk = (l >> 4) * 8;

  auto compute = [&](int buf) {
    bf16x8 a[8], b[4];
    #pragma unroll
    for (int m = 0; m < 8; ++m) a[m] = *(const bf16x8*)&lds[buf][0][wr + m * 16 + lr][lk];
    #pragma unroll
    for (int n = 0; n < 4; ++n) b[n] = *(const bf16x8*)&lds[buf][1][wc + n * 16 + lr][lk];
    #pragma unroll
    for (int m = 0; m < 8; ++m)
      #pragma unroll
      for (int n = 0; n < 4; ++n)
        acc[m][n] = __builtin_amdgcn_mfma_f32_16x16x32_bf16(a[m], b[n], acc[m][n], 0, 0, 0);
  };

  // prologue: tile0 -> buf0 (compiler waits the regs); prefetch B(1).
  issueA(0); issueB(0, brE);
  writeA(0); writeB(brE, 0);
  issueB(1, brO);
  LGKM0(); RAWBAR();

  // bodies kt = 0..nk-3 in even/odd pairs (nk-2 even), then leftover + tail.
  for (int kt = 0; kt < nk - 2; kt += 2) {
    // even body (cur=0): fill buf1 with tile kt+1; prefetch B(kt+2).
    issueA(kt + 1);
    issueB(kt + 2, brE);
    compute(0);
    writeA(1);              // waits A(kt+1) regs only
    writeB(brO, 1);         // waits B(kt+1) regs only; B(kt+2) stays in flight
    LGKM0(); RAWBAR();
    // odd body (cur=1): fill buf0 with tile kt+2; prefetch B(kt+3).
    issueA(kt + 2);
    issueB(kt + 3, brO);
    compute(1);
    writeA(0);
    writeB(brE, 0);
    LGKM0(); RAWBAR();
  }
  // leftover even body kt = nk-2: fill buf1 with tile nk-1 (B from brO).
  issueA(nk - 1);
  compute(0);
  writeA(1);
  writeB(brO, 1);
  LGKM0(); RAWBAR();
  compute(1);

  // epilogue: C/D layout col=lane&15, row=(lane>>4)*4+j (m89-verified)
  #pragma unroll
  for (int m = 0; m < 8; ++m) {
    #pragma unroll
    for (int n = 0; n < 4; ++n) {
      const int col = nb * 256 + wc + n * 16 + lr;
      const float bc = bias[col];
      #pragma unroll
      for (int j = 0; j < 4; ++j) {
        const int lrow = mlocal * 256 + wr + m * 16 + (l >> 4) * 4 + j;
        if (lrow >= mcnt) continue;
        float v = acc[m][n][j] + bc;
        C[(long)lrow * F_DIM + col] = f2bf(gelu_exact(v));
      }
    }
  }
}

// ---------------------------------------------------------------- grouped GEMM2
// Flat grid. 128x128, BK=32, 4 waves, 2-phase, all-reg-staged (same scheme).
// C = (A @ B^T + bias)[*rowscale] f32. K=4096, N=1024, NB=8.
__global__ __launch_bounds__(256)
void moe_gemm2(const unsigned short* __restrict__ hbuf,
               const float* __restrict__ Wsh, const float* __restrict__ Wrt,
               const float* __restrict__ bsh, const float* __restrict__ brt,
               float* __restrict__ out, float* __restrict__ rout,
               const float* __restrict__ bwgt,
               const int* __restrict__ cnts, const int* __restrict__ offs,
               const int* __restrict__ tt) {
  __shared__ __align__(16) unsigned short lds[2][2][128][32];   // 32 KB
  const int wid = xcd_swizzle(blockIdx.x, G2_GRID);
  const int mt = wid >> 3, nb = wid & 7;
  if (mt >= tt[9]) return;
  int z = 0;
  while (mt >= tt[z + 1]) ++z;
  const int mlocal = mt - tt[z];

  const unsigned short* A;
  const float* Bp;
  const float* bias;
  float* C;
  const float* rs = nullptr;
  int mcnt;
  if (z == NEXP) {
    A = hbuf; Bp = Wsh; bias = bsh; C = out; mcnt = T_TOK;
  } else {
    const int off = offs[z];
    mcnt = cnts[z];
    A = hbuf + ((long)T_TOK + off) * F_DIM;
    Bp = Wrt + (long)z * H_DIM * F_DIM;
    bias = brt + z * H_DIM;
    C = rout + (long)off * H_DIM;
    rs = bwgt + off;
  }

  const int t = threadIdx.x;
  f32x4 acc[4][4] = {};
  const int nk = F_DIM >> 5;           // 128 K-steps (even)

  const int srow = t >> 2;             // 0..63 (+ i*64)
  const int scol = (t & 3) * 8;

  u16x8 ar[2];
  f32x4 brE[4], brO[4];

  auto issueA = [&](int kt) {
    #pragma unroll
    for (int i = 0; i < 2; ++i)
      ar[i] = *(const u16x8*)(A + (long)(mlocal * 128 + i * 64 + srow) * F_DIM + kt * 32 + scol);
  };
  auto writeA = [&](int buf) {
    #pragma unroll
    for (int i = 0; i < 2; ++i)
      *(u16x8*)&lds[buf][0][i * 64 + srow][scol] = ar[i];
  };
  auto issueB = [&](int kt, f32x4* br) {
    #pragma unroll
    for (int i = 0; i < 2; ++i) {
      const float* g = Bp + (long)(nb * 128 + i * 64 + srow) * F_DIM + kt * 32 + scol;
      br[i * 2]     = *(const f32x4*)g;
      br[i * 2 + 1] = *(const f32x4*)(g + 4);
    }
  };
  auto writeB = [&](const f32x4* br, int buf) {
    #pragma unroll
    for (int i = 0; i < 2; ++i) {
      u16x8 o;
      #pragma unroll
      for (int j = 0; j < 4; ++j) {
        o[j]     = f2bf(br[i * 2][j]);
        o[4 + j] = f2bf(br[i * 2 + 1][j]);
      }
      *(u16x8*)&lds[buf][1][i * 64 + srow][scol] = o;
    }
  };

  const int l = t & 63;
  const int w = t >> 6;
  const int wr = (w >> 1) * 64, wc = (w & 1) * 64;
  const int lr = l & 15, lk = (l >> 4) * 8;

  auto compute = [&](int buf) {
    bf16x8 a[4], b[4];
    #pragma unroll
    for (int m = 0; m < 4; ++m) a[m] = *(const bf16x8*)&lds[buf][0][wr + m * 16 + lr][lk];
    #pragma unroll
    for (int n = 0; n < 4; ++n) b[n] = *(const bf16x8*)&lds[buf][1][wc + n * 16 + lr][lk];
    #pragma unroll
    for (int m = 0; m < 4; ++m)
      #pragma unroll
      for (int n = 0; n < 4; ++n)
        acc[m][n] = __builtin_amdgcn_mfma_f32_16x16x32_bf16(a[m], b[n], acc[m][n], 0, 0, 0);
  };

  issueA(0); issueB(0, brE);
  writeA(0); writeB(brE, 0);
  issueB(1, brO);
  LGKM0(); RAWBAR();

  for (int kt = 0; kt < nk - 2; kt += 2) {
    issueA(kt + 1);
    issueB(kt + 2, brE);
    compute(0);
    writeA(1);
    writeB(brO, 1);
    LGKM0(); RAWBAR();
    issueA(kt + 2);
    issueB(kt + 3, brO);
    compute(1);
    writeA(0);
    writeB(brE, 0);
    LGKM0(); RAWBAR();
  }
  issueA(nk - 1);
  compute(0);
  writeA(1);
  writeB(brO, 1);
  LGKM0(); RAWBAR();
  compute(1);

  const bool has_rs = (z != NEXP);
  #pragma unroll
  for (int m = 0; m < 4; ++m) {
    #pragma unroll
    for (int n = 0; n < 4; ++n) {
      const int col = nb * 128 + wc + n * 16 + lr;
      const float bc = bias[col];
      #pragma unroll
      for (int j = 0; j < 4; ++j) {
        const int lrow = mlocal * 128 + wr + m * 16 + (l >> 4) * 4 + j;
        if (lrow >= mcnt) continue;
        float v = acc[m][n][j] + bc;
        if (has_rs) v *= rs[lrow];
        C[(long)lrow * H_DIM + col] = v;
      }
    }
  }
}

// ---------------------------------------------------------------- host

extern "C" void kernel_launch(void* const* d_in, const int* in_sizes, int n_in,
                              void* d_out, int out_size, void* d_ws, size_t ws_size,
                              hipStream_t stream) {
  const float* x   = (const float*)d_in[0];
  const float* gw  = (const float*)d_in[1];
  const float* gb  = (const float*)d_in[2];
  const float* rb  = (const float*)d_in[3];
  const float* sw1 = (const float*)d_in[4];
  const float* sb1 = (const float*)d_in[5];
  const float* sw2 = (const float*)d_in[6];
  const float* sb2 = (const float*)d_in[7];
  const float* ew1 = (const float*)d_in[8];
  const float* eb1 = (const float*)d_in[9];
  const float* ew2 = (const float*)d_in[10];
  const float* eb2 = (const float*)d_in[11];

  char* wsp = (char*)d_ws;
  size_t o = 0;
  auto alloc = [&](size_t b) -> void* {
    void* p = wsp + o;
    o = (o + b + 255) & ~(size_t)255;
    return p;
  };
  unsigned short* x_bf = (unsigned short*)alloc((size_t)T_TOK * H_DIM * 2);
  unsigned short* gx   = (unsigned short*)alloc((size_t)(RT + RPAD) * H_DIM * 2);
  unsigned short* hbuf = (unsigned short*)alloc((size_t)(T_TOK + RT + RPAD) * F_DIM * 2);
  float* rout          = (float*)alloc((size_t)RT * H_DIM * 4);
  int*   tok_e  = (int*)alloc(2 * T_TOK * 4);
  float* tok_w  = (float*)alloc(2 * T_TOK * 4);
  int*   tokpos = (int*)alloc(2 * T_TOK * 4);
  int*   btok   = (int*)alloc(RT * 4);
  float* bw     = (float*)alloc(RT * 4);
  int*   meta   = (int*)alloc(1024);
  int* counts = meta, *cursor = meta + 8, *offs = meta + 16;
  int* t1off = meta + 32, *t2off = meta + 48;
  (void)ws_size; (void)in_sizes; (void)n_in; (void)out_size;

  float* out = (float*)d_out;

  zero_kernel<<<1, 64, 0, stream>>>(meta);
  gate_kernel<<<T_TOK, 64, 0, stream>>>(x, gw, gb, rb, x_bf, tok_e, tok_w, counts);
  scan_kernel<<<1, 1, 0, stream>>>(counts, offs, t1off, t2off);
  build_kernel<<<T_TOK / 256, 256, 0, stream>>>(tok_e, tok_w, offs, cursor, btok, bw, tokpos);
  gather_kernel<<<RT, 128, 0, stream>>>(x_bf, btok, gx);

  // GEMM1: K=1024, N=4096; fp32 weights fused-converted (reg-staged).
  moe_gemm1<<<G1_GRID, 512, 0, stream>>>(
      x_bf, gx, sw1, ew1, sb1, eb1,
      hbuf, hbuf + (size_t)T_TOK * F_DIM, counts, offs, t1off);

  // GEMM2: K=4096, N=1024.
  moe_gemm2<<<G2_GRID, 256, 0, stream>>>(
      hbuf, sw2, ew2, sb2, eb2, out, rout, bw, counts, offs, t2off);

  combine_kernel<<<T_TOK, 256, 0, stream>>>(out, rout, tokpos);
}

// Round 11
// 725.660 us; speedup vs baseline: 1.0040x; 1.0040x over previous
//
#include <hip/hip_runtime.h>
#include <hip/hip_bf16.h>
#include <math.h>

// DeepSeekMoE: T=4096, H=1024, F=4096, E=8, top-2 sigmoid routing.
// Round 11: consolidation on r7 (best known: flat balanced grids, 2-phase
// global_load_lds GEMMs, separate bf16 weight-convert pass — the fused-convert
// lane is closed: r8/r9 incorrect, r10 net-negative). New: combine pass fused
// into gemm2 epilogue via atomicAdd into memset-0 out (saves ~110 MB traffic
// + one launch). rout/tokpos/combine removed.

#define T_TOK 4096
#define H_DIM 1024
#define F_DIM 4096
#define NEXP  8
#define RT    (2 * T_TOK)
#define RPAD  512

// worst-case flat grid sizes (fixed for graph capture)
#define G1_TILES 56    // 16 shared + max 40 expert M-tiles (BM=256)
#define G2_TILES 104   // 32 shared + max 72 expert M-tiles (BM=128)
#define G1_GRID  (G1_TILES * 16)   // NB1 = F/256 = 16
#define G2_GRID  (G2_TILES * 8)    // NB2 = H/128 = 8

typedef __bf16 bf16_t;
typedef __bf16 bf16x8 __attribute__((ext_vector_type(8)));
typedef float  f32x4  __attribute__((ext_vector_type(4)));
typedef unsigned short u16x8 __attribute__((ext_vector_type(8)));

__device__ __forceinline__ unsigned short f2bf(float f) {
  union { bf16_t b; unsigned short u; } cv;
  cv.b = (bf16_t)f;
  return cv.u;
}

__device__ __forceinline__ float gelu_exact(float v) {
  return 0.5f * v * (1.0f + erff(v * 0.70710678118654752f));
}

// bijective XCD swizzle (m204)
__device__ __forceinline__ int xcd_swizzle(int orig, int nwg) {
  const int q = nwg >> 3, r = nwg & 7;
  const int xcd = orig & 7, idx = orig >> 3;
  return (xcd < r ? xcd * (q + 1) : r * (q + 1) + (xcd - r) * q) + idx;
}

// ---------------------------------------------------------------- small kernels

__global__ void zero_kernel(int* p) {
  if (threadIdx.x < 16) p[threadIdx.x] = 0;
}

// all four weight tensors -> contiguous bf16 dst (w1s|w2s|w1e|w2e)
__global__ void convert4_kernel(const float* __restrict__ s0, const float* __restrict__ s1,
                                const float* __restrict__ s2, const float* __restrict__ s3,
                                unsigned short* __restrict__ dst) {
  const long N0 = (long)F_DIM * H_DIM / 8;
  const long N1 = N0 + (long)H_DIM * F_DIM / 8;
  const long N2 = N1 + (long)NEXP * F_DIM * H_DIM / 8;
  const long NT = N2 + (long)NEXP * H_DIM * F_DIM / 8;
  long i = (long)blockIdx.x * blockDim.x + threadIdx.x;
  const long stride = (long)gridDim.x * blockDim.x;
  for (; i < NT; i += stride) {
    const float* s; long j;
    if (i < N0)      { s = s0; j = i; }
    else if (i < N1) { s = s1; j = i - N0; }
    else if (i < N2) { s = s2; j = i - N1; }
    else             { s = s3; j = i - N2; }
    const f32x4* sp = (const f32x4*)s + j * 2;
    f32x4 v0 = sp[0], v1 = sp[1];
    u16x8 o;
    #pragma unroll
    for (int k = 0; k < 4; ++k) { o[k] = f2bf(v0[k]); o[4 + k] = f2bf(v1[k]); }
    *(u16x8*)(dst + i * 8) = o;
  }
}

// one wave per token: 8 gate scores -> sigmoid -> top2; also emits x in bf16
__global__ void gate_kernel(const float* __restrict__ x, const float* __restrict__ gw,
                            const float* __restrict__ gb, const float* __restrict__ rb,
                            unsigned short* __restrict__ x_bf,
                            int* __restrict__ tok_e, float* __restrict__ tok_w,
                            int* __restrict__ counts) {
  int tkn = blockIdx.x;
  int lane = threadIdx.x;
  float acc[NEXP];
  #pragma unroll
  for (int e = 0; e < NEXP; ++e) acc[e] = 0.f;
  const float* xr = x + (long)tkn * H_DIM;
  unsigned short* xbr = x_bf + (long)tkn * H_DIM;
  for (int k = lane; k < H_DIM; k += 64) {
    float xv = xr[k];
    xbr[k] = f2bf(xv);
    #pragma unroll
    for (int e = 0; e < NEXP; ++e) acc[e] += xv * gw[e * H_DIM + k];
  }
  #pragma unroll
  for (int off = 32; off > 0; off >>= 1) {
    #pragma unroll
    for (int e = 0; e < NEXP; ++e) acc[e] += __shfl_xor(acc[e], off, 64);
  }
  if (lane == 0) {
    float s[NEXP];
    #pragma unroll
    for (int e = 0; e < NEXP; ++e)
      s[e] = 1.f / (1.f + expf(-(acc[e] + gb[e] + rb[e])));
    int e0 = 0;
    #pragma unroll
    for (int e = 1; e < NEXP; ++e) if (s[e] > s[e0]) e0 = e;
    int e1 = (e0 == 0) ? 1 : 0;
    #pragma unroll
    for (int e = 0; e < NEXP; ++e) if (e != e0 && e != e1 && s[e] > s[e1]) e1 = e;
    tok_e[2 * tkn] = e0;  tok_e[2 * tkn + 1] = e1;
    tok_w[2 * tkn] = s[e0]; tok_w[2 * tkn + 1] = s[e1];
    atomicAdd(&counts[e0], 1);
    atomicAdd(&counts[e1], 1);
  }
}

// row offsets + per-group M-tile offset tables for both GEMMs.
__global__ void scan_kernel(const int* __restrict__ counts, int* __restrict__ offs,
                            int* __restrict__ t1, int* __restrict__ t2) {
  if (threadIdx.x == 0) {
    int o = 0, a1 = 0, a2 = 0;
    for (int e = 0; e < NEXP; ++e) {
      offs[e] = o;
      t1[e] = a1; t2[e] = a2;
      a1 += (counts[e] + 255) >> 8;
      a2 += (counts[e] + 127) >> 7;
      o += counts[e];
    }
    t1[8] = a1; t2[8] = a2;
    t1[9] = a1 + (T_TOK >> 8);
    t2[9] = a2 + (T_TOK >> 7);
  }
}

__global__ void build_kernel(const int* __restrict__ tok_e, const float* __restrict__ tok_w,
                             const int* __restrict__ offs, int* __restrict__ cursor,
                             int* __restrict__ btok, float* __restrict__ bw) {
  int tkn = blockIdx.x * blockDim.x + threadIdx.x;
  if (tkn >= T_TOK) return;
  #pragma unroll
  for (int k = 0; k < 2; ++k) {
    int e = tok_e[2 * tkn + k];
    int p = offs[e] + atomicAdd(&cursor[e], 1);
    btok[p] = tkn;
    bw[p] = tok_w[2 * tkn + k];
  }
}

// copy x_bf row -> gathered bf16 row, bucket order (16B/thread)
__global__ void gather_kernel(const unsigned short* __restrict__ x_bf,
                              const int* __restrict__ btok,
                              unsigned short* __restrict__ gx) {
  int p = blockIdx.x, tid = threadIdx.x;   // 128 threads * 8 bf16
  int tkn = btok[p];
  u16x8 v = *(const u16x8*)(x_bf + (long)tkn * H_DIM + tid * 8);
  *(u16x8*)(gx + (long)p * H_DIM + tid * 8) = v;
}

// ---------------------------------------------------------------- grouped GEMM1
// Flat grid over real tiles. 256x256, BK=32, 8 waves, 2-phase (r3/r7-proven).
// C = gelu(A @ B^T + bias) bf16. K=1024, N=4096, NB=16.
__global__ __launch_bounds__(512)
void moe_gemm1(const unsigned short* __restrict__ Ash, const unsigned short* __restrict__ Art,
               const unsigned short* __restrict__ Wsh, const unsigned short* __restrict__ Wrt,
               const float* __restrict__ bsh, const float* __restrict__ brt,
               unsigned short* __restrict__ Csh, unsigned short* __restrict__ Crt,
               const int* __restrict__ cnts, const int* __restrict__ offs,
               const int* __restrict__ tt) {
  __shared__ __align__(16) unsigned short lds[2][2][256][32];   // 64 KB
  const int wid = xcd_swizzle(blockIdx.x, G1_GRID);
  const int mt = wid >> 4, nb = wid & 15;
  if (mt >= tt[9]) return;
  int z = 0;
  while (mt >= tt[z + 1]) ++z;
  const int mlocal = mt - tt[z];

  const unsigned short* A;
  const unsigned short* Bp;
  const float* bias;
  unsigned short* C;
  int mcnt;
  if (z == NEXP) {
    A = Ash; Bp = Wsh; bias = bsh; C = Csh; mcnt = T_TOK;
  } else {
    const int off = offs[z];
    mcnt = cnts[z];
    A = Art + (long)off * H_DIM;
    Bp = Wrt + (long)z * F_DIM * H_DIM;
    bias = brt + z * F_DIM;
    C = Crt + (long)off * F_DIM;
  }

  const int t = threadIdx.x;
  f32x4 acc[8][4] = {};
  const int nk = H_DIM >> 5;   // 32 K-steps

  auto stage = [&](int kt, int buf) {
    #pragma unroll
    for (int i = 0; i < 2; ++i) {
      const int row = i * 128 + (t >> 2);
      const int ch = (t & 3) * 8;
      const unsigned short* ga = A + (long)(mlocal * 256 + row) * H_DIM + kt * 32 + ch;
      const unsigned short* gb = Bp + (long)(nb * 256 + row) * H_DIM + kt * 32 + ch;
      unsigned short* la = &lds[buf][0][0][0] + i * 4096 + t * 8;
      unsigned short* lb = &lds[buf][1][0][0] + i * 4096 + t * 8;
      __builtin_amdgcn_global_load_lds((const __attribute__((address_space(1))) unsigned int*)ga,
                                       (__attribute__((address_space(3))) unsigned int*)la, 16, 0, 0);
      __builtin_amdgcn_global_load_lds((const __attribute__((address_space(1))) unsigned int*)gb,
                                       (__attribute__((address_space(3))) unsigned int*)lb, 16, 0, 0);
    }
  };

  const int l = t & 63;
  const int w = t >> 6;                       // 8 waves: 2M x 4N
  const int wr = (w >> 2) * 128, wc = (w & 3) * 64;
  const int lr = l & 15, lk = (l >> 4) * 8;

  auto compute = [&](int buf) {
    bf16x8 a[8], b[4];
    #pragma unroll
    for (int m = 0; m < 8; ++m) a[m] = *(const bf16x8*)&lds[buf][0][wr + m * 16 + lr][lk];
    #pragma unroll
    for (int n = 0; n < 4; ++n) b[n] = *(const bf16x8*)&lds[buf][1][wc + n * 16 + lr][lk];
    #pragma unroll
    for (int m = 0; m < 8; ++m)
      #pragma unroll
      for (int n = 0; n < 4; ++n)
        acc[m][n] = __builtin_amdgcn_mfma_f32_16x16x32_bf16(a[m], b[n], acc[m][n], 0, 0, 0);
  };

  stage(0, 0);
  asm volatile("s_waitcnt vmcnt(0)" ::: "memory");
  __syncthreads();
  for (int kt = 0; kt < nk - 1; ++kt) {
    const int cur = kt & 1;
    stage(kt + 1, cur ^ 1);
    compute(cur);
    asm volatile("s_waitcnt vmcnt(0)" ::: "memory");
    __syncthreads();
  }
  compute((nk - 1) & 1);

  // epilogue: C/D layout col=lane&15, row=(lane>>4)*4+j (m89-verified)
  #pragma unroll
  for (int m = 0; m < 8; ++m) {
    #pragma unroll
    for (int n = 0; n < 4; ++n) {
      const int col = nb * 256 + wc + n * 16 + lr;
      const float bc = bias[col];
      #pragma unroll
      for (int j = 0; j < 4; ++j) {
        const int lrow = mlocal * 256 + wr + m * 16 + (l >> 4) * 4 + j;
        if (lrow >= mcnt) continue;
        float v = acc[m][n][j] + bc;
        C[(long)lrow * F_DIM + col] = f2bf(gelu_exact(v));
      }
    }
  }
}

// ---------------------------------------------------------------- grouped GEMM2
// Flat grid. 128x128, BK=32, 4 waves, 2-phase. Epilogue: atomicAdd directly
// into out (memset-0 before launch): shared adds (acc+bias) at row lrow;
// expert adds (acc+bias)*bw at row btok[off+lrow]. K=4096, N=1024, NB=8.
__global__ __launch_bounds__(256)
void moe_gemm2(const unsigned short* __restrict__ hbuf,
               const unsigned short* __restrict__ Wsh, const unsigned short* __restrict__ Wrt,
               const float* __restrict__ bsh, const float* __restrict__ brt,
               float* __restrict__ out,
               const float* __restrict__ bwgt, const int* __restrict__ btok,
               const int* __restrict__ cnts, const int* __restrict__ offs,
               const int* __restrict__ tt) {
  __shared__ __align__(16) unsigned short lds[2][2][128][32];   // 32 KB
  const int wid = xcd_swizzle(blockIdx.x, G2_GRID);
  const int mt = wid >> 3, nb = wid & 7;
  if (mt >= tt[9]) return;
  int z = 0;
  while (mt >= tt[z + 1]) ++z;
  const int mlocal = mt - tt[z];

  const unsigned short* A;
  const unsigned short* Bp;
  const float* bias;
  const float* rs = nullptr;
  const int* bt = nullptr;
  int mcnt;
  if (z == NEXP) {
    A = hbuf; Bp = Wsh; bias = bsh; mcnt = T_TOK;
  } else {
    const int off = offs[z];
    mcnt = cnts[z];
    A = hbuf + ((long)T_TOK + off) * F_DIM;
    Bp = Wrt + (long)z * H_DIM * F_DIM;
    bias = brt + z * H_DIM;
    rs = bwgt + off;
    bt = btok + off;
  }
  if (mlocal * 128 >= mcnt) { /* unreachable: tile tables exact */ }

  const int t = threadIdx.x;
  f32x4 acc[4][4] = {};
  const int nk = F_DIM >> 5;   // 128 K-steps

  auto stage = [&](int kt, int buf) {
    #pragma unroll
    for (int i = 0; i < 2; ++i) {
      const int row = i * 64 + (t >> 2);
      const int ch = (t & 3) * 8;
      const unsigned short* ga = A + (long)(mlocal * 128 + row) * F_DIM + kt * 32 + ch;
      const unsigned short* gb = Bp + (long)(nb * 128 + row) * F_DIM + kt * 32 + ch;
      unsigned short* la = &lds[buf][0][0][0] + i * 2048 + t * 8;
      unsigned short* lb = &lds[buf][1][0][0] + i * 2048 + t * 8;
      __builtin_amdgcn_global_load_lds((const __attribute__((address_space(1))) unsigned int*)ga,
                                       (__attribute__((address_space(3))) unsigned int*)la, 16, 0, 0);
      __builtin_amdgcn_global_load_lds((const __attribute__((address_space(1))) unsigned int*)gb,
                                       (__attribute__((address_space(3))) unsigned int*)lb, 16, 0, 0);
    }
  };

  const int l = t & 63;
  const int w = t >> 6;
  const int wr = (w >> 1) * 64, wc = (w & 1) * 64;
  const int lr = l & 15, lk = (l >> 4) * 8;

  auto compute = [&](int buf) {
    bf16x8 a[4], b[4];
    #pragma unroll
    for (int m = 0; m < 4; ++m) a[m] = *(const bf16x8*)&lds[buf][0][wr + m * 16 + lr][lk];
    #pragma unroll
    for (int n = 0; n < 4; ++n) b[n] = *(const bf16x8*)&lds[buf][1][wc + n * 16 + lr][lk];
    #pragma unroll
    for (int m = 0; m < 4; ++m)
      #pragma unroll
      for (int n = 0; n < 4; ++n)
        acc[m][n] = __builtin_amdgcn_mfma_f32_16x16x32_bf16(a[m], b[n], acc[m][n], 0, 0, 0);
  };

  stage(0, 0);
  asm volatile("s_waitcnt vmcnt(0)" ::: "memory");
  __syncthreads();
  for (int kt = 0; kt < nk - 1; ++kt) {
    const int cur = kt & 1;
    stage(kt + 1, cur ^ 1);
    compute(cur);
    asm volatile("s_waitcnt vmcnt(0)" ::: "memory");
    __syncthreads();
  }
  compute((nk - 1) & 1);

  const bool routed = (z != NEXP);
  #pragma unroll
  for (int m = 0; m < 4; ++m) {
    #pragma unroll
    for (int n = 0; n < 4; ++n) {
      const int col = nb * 128 + wc + n * 16 + lr;
      const float bc = bias[col];
      #pragma unroll
      for (int j = 0; j < 4; ++j) {
        const int lrow = mlocal * 128 + wr + m * 16 + (l >> 4) * 4 + j;
        if (lrow >= mcnt) continue;
        float v = acc[m][n][j] + bc;
        long orow;
        if (routed) { v *= rs[lrow]; orow = bt[lrow]; }
        else        { orow = lrow; }
        atomicAdd(&out[orow * H_DIM + col], v);
      }
    }
  }
}

// ---------------------------------------------------------------- host

extern "C" void kernel_launch(void* const* d_in, const int* in_sizes, int n_in,
                              void* d_out, int out_size, void* d_ws, size_t ws_size,
                              hipStream_t stream) {
  const float* x   = (const float*)d_in[0];
  const float* gw  = (const float*)d_in[1];
  const float* gb  = (const float*)d_in[2];
  const float* rb  = (const float*)d_in[3];
  const float* sw1 = (const float*)d_in[4];
  const float* sb1 = (const float*)d_in[5];
  const float* sw2 = (const float*)d_in[6];
  const float* sb2 = (const float*)d_in[7];
  const float* ew1 = (const float*)d_in[8];
  const float* eb1 = (const float*)d_in[9];
  const float* ew2 = (const float*)d_in[10];
  const float* eb2 = (const float*)d_in[11];

  char* wsp = (char*)d_ws;
  size_t o = 0;
  auto alloc = [&](size_t b) -> void* {
    void* p = wsp + o;
    o = (o + b + 255) & ~(size_t)255;
    return p;
  };
  unsigned short* x_bf = (unsigned short*)alloc((size_t)T_TOK * H_DIM * 2);
  // w1s|w2s|w1e|w2e contiguous (convert4 writes one flat dst)
  unsigned short* w1s  = (unsigned short*)alloc((size_t)F_DIM * H_DIM * 2);
  unsigned short* w2s  = (unsigned short*)alloc((size_t)H_DIM * F_DIM * 2);
  unsigned short* w1e  = (unsigned short*)alloc((size_t)NEXP * F_DIM * H_DIM * 2);
  unsigned short* w2e  = (unsigned short*)alloc((size_t)NEXP * H_DIM * F_DIM * 2);
  unsigned short* gx   = (unsigned short*)alloc((size_t)(RT + RPAD) * H_DIM * 2);
  unsigned short* hbuf = (unsigned short*)alloc((size_t)(T_TOK + RT + RPAD) * F_DIM * 2);
  int*   tok_e  = (int*)alloc(2 * T_TOK * 4);
  float* tok_w  = (float*)alloc(2 * T_TOK * 4);
  int*   btok   = (int*)alloc(RT * 4);
  float* bw     = (float*)alloc(RT * 4);
  int*   meta   = (int*)alloc(1024);
  int* counts = meta, *cursor = meta + 8, *offs = meta + 16;
  int* t1off = meta + 32, *t2off = meta + 48;
  (void)ws_size; (void)in_sizes; (void)n_in;

  float* out = (float*)d_out;

  zero_kernel<<<1, 64, 0, stream>>>(meta);
  hipMemsetAsync(d_out, 0, (size_t)out_size * 4, stream);   // out accumulated atomically
  convert4_kernel<<<4096, 256, 0, stream>>>(sw1, sw2, ew1, ew2, w1s);
  gate_kernel<<<T_TOK, 64, 0, stream>>>(x, gw, gb, rb, x_bf, tok_e, tok_w, counts);
  scan_kernel<<<1, 1, 0, stream>>>(counts, offs, t1off, t2off);
  build_kernel<<<T_TOK / 256, 256, 0, stream>>>(tok_e, tok_w, offs, cursor, btok, bw);
  gather_kernel<<<RT, 128, 0, stream>>>(x_bf, btok, gx);

  // GEMM1: K=1024, N=4096; flat balanced grid.
  moe_gemm1<<<G1_GRID, 512, 0, stream>>>(
      x_bf, gx, w1s, w1e, sb1, eb1,
      hbuf, hbuf + (size_t)T_TOK * F_DIM, counts, offs, t1off);

  // GEMM2: K=4096, N=1024; epilogue scatters atomically into out.
  moe_gemm2<<<G2_GRID, 256, 0, stream>>>(
      hbuf, w2s, w2e, sb2, eb2, out, bw, btok, counts, offs, t2off);
}

// Round 12
// 627.961 us; speedup vs baseline: 1.1602x; 1.1556x over previous
//
#include <hip/hip_runtime.h>
#include <hip/hip_bf16.h>
#include <math.h>

// DeepSeekMoE: T=4096, H=1024, F=4096, E=8, top-2 sigmoid routing.
// Round 12: r7 base (best: 697us; flat balanced grids, 2-phase gload_lds GEMMs,
// separate weight-convert, separate combine). Changes:
//  (1) gather fused into gemm1 A-staging via per-lane btok-indexed gload_lds
//      source (gather kernel + gx buffer removed).
//  (2) gemm2: 512 threads / 8 waves (2Mx4N, acc[4][2]) at same 128^2 tile for
//      more co-resident waves per CU (barrier-drain hiding, m114/m233).
// Closed lanes: 8-phase (r4/r6), fused convert (r5/r8-r10), atomic combine (r11).

#define T_TOK 4096
#define H_DIM 1024
#define F_DIM 4096
#define NEXP  8
#define RT    (2 * T_TOK)
#define RPAD  512

// worst-case flat grid sizes (fixed for graph capture)
#define G1_TILES 56    // 16 shared + max 40 expert M-tiles (BM=256)
#define G2_TILES 104   // 32 shared + max 72 expert M-tiles (BM=128)
#define G1_GRID  (G1_TILES * 16)   // NB1 = F/256 = 16
#define G2_GRID  (G2_TILES * 8)    // NB2 = H/128 = 8

typedef __bf16 bf16_t;
typedef __bf16 bf16x8 __attribute__((ext_vector_type(8)));
typedef float  f32x4  __attribute__((ext_vector_type(4)));
typedef unsigned short u16x8 __attribute__((ext_vector_type(8)));

__device__ __forceinline__ unsigned short f2bf(float f) {
  union { bf16_t b; unsigned short u; } cv;
  cv.b = (bf16_t)f;
  return cv.u;
}

__device__ __forceinline__ float gelu_exact(float v) {
  return 0.5f * v * (1.0f + erff(v * 0.70710678118654752f));
}

// bijective XCD swizzle (m204)
__device__ __forceinline__ int xcd_swizzle(int orig, int nwg) {
  const int q = nwg >> 3, r = nwg & 7;
  const int xcd = orig & 7, idx = orig >> 3;
  return (xcd < r ? xcd * (q + 1) : r * (q + 1) + (xcd - r) * q) + idx;
}

// ---------------------------------------------------------------- small kernels

__global__ void zero_kernel(int* p) {
  if (threadIdx.x < 16) p[threadIdx.x] = 0;
}

// all four weight tensors -> contiguous bf16 dst (w1s|w2s|w1e|w2e)
__global__ void convert4_kernel(const float* __restrict__ s0, const float* __restrict__ s1,
                                const float* __restrict__ s2, const float* __restrict__ s3,
                                unsigned short* __restrict__ dst) {
  const long N0 = (long)F_DIM * H_DIM / 8;
  const long N1 = N0 + (long)H_DIM * F_DIM / 8;
  const long N2 = N1 + (long)NEXP * F_DIM * H_DIM / 8;
  const long NT = N2 + (long)NEXP * H_DIM * F_DIM / 8;
  long i = (long)blockIdx.x * blockDim.x + threadIdx.x;
  const long stride = (long)gridDim.x * blockDim.x;
  for (; i < NT; i += stride) {
    const float* s; long j;
    if (i < N0)      { s = s0; j = i; }
    else if (i < N1) { s = s1; j = i - N0; }
    else if (i < N2) { s = s2; j = i - N1; }
    else             { s = s3; j = i - N2; }
    const f32x4* sp = (const f32x4*)s + j * 2;
    f32x4 v0 = sp[0], v1 = sp[1];
    u16x8 o;
    #pragma unroll
    for (int k = 0; k < 4; ++k) { o[k] = f2bf(v0[k]); o[4 + k] = f2bf(v1[k]); }
    *(u16x8*)(dst + i * 8) = o;
  }
}

// one wave per token: 8 gate scores -> sigmoid -> top2; also emits x in bf16
__global__ void gate_kernel(const float* __restrict__ x, const float* __restrict__ gw,
                            const float* __restrict__ gb, const float* __restrict__ rb,
                            unsigned short* __restrict__ x_bf,
                            int* __restrict__ tok_e, float* __restrict__ tok_w,
                            int* __restrict__ counts) {
  int tkn = blockIdx.x;
  int lane = threadIdx.x;
  float acc[NEXP];
  #pragma unroll
  for (int e = 0; e < NEXP; ++e) acc[e] = 0.f;
  const float* xr = x + (long)tkn * H_DIM;
  unsigned short* xbr = x_bf + (long)tkn * H_DIM;
  for (int k = lane; k < H_DIM; k += 64) {
    float xv = xr[k];
    xbr[k] = f2bf(xv);
    #pragma unroll
    for (int e = 0; e < NEXP; ++e) acc[e] += xv * gw[e * H_DIM + k];
  }
  #pragma unroll
  for (int off = 32; off > 0; off >>= 1) {
    #pragma unroll
    for (int e = 0; e < NEXP; ++e) acc[e] += __shfl_xor(acc[e], off, 64);
  }
  if (lane == 0) {
    float s[NEXP];
    #pragma unroll
    for (int e = 0; e < NEXP; ++e)
      s[e] = 1.f / (1.f + expf(-(acc[e] + gb[e] + rb[e])));
    int e0 = 0;
    #pragma unroll
    for (int e = 1; e < NEXP; ++e) if (s[e] > s[e0]) e0 = e;
    int e1 = (e0 == 0) ? 1 : 0;
    #pragma unroll
    for (int e = 0; e < NEXP; ++e) if (e != e0 && e != e1 && s[e] > s[e1]) e1 = e;
    tok_e[2 * tkn] = e0;  tok_e[2 * tkn + 1] = e1;
    tok_w[2 * tkn] = s[e0]; tok_w[2 * tkn + 1] = s[e1];
    atomicAdd(&counts[e0], 1);
    atomicAdd(&counts[e1], 1);
  }
}

// row offsets + per-group M-tile offset tables for both GEMMs.
__global__ void scan_kernel(const int* __restrict__ counts, int* __restrict__ offs,
                            int* __restrict__ t1, int* __restrict__ t2) {
  if (threadIdx.x == 0) {
    int o = 0, a1 = 0, a2 = 0;
    for (int e = 0; e < NEXP; ++e) {
      offs[e] = o;
      t1[e] = a1; t2[e] = a2;
      a1 += (counts[e] + 255) >> 8;
      a2 += (counts[e] + 127) >> 7;
      o += counts[e];
    }
    t1[8] = a1; t2[8] = a2;
    t1[9] = a1 + (T_TOK >> 8);
    t2[9] = a2 + (T_TOK >> 7);
  }
}

__global__ void build_kernel(const int* __restrict__ tok_e, const float* __restrict__ tok_w,
                             const int* __restrict__ offs, int* __restrict__ cursor,
                             int* __restrict__ btok, float* __restrict__ bw,
                             int* __restrict__ tokpos) {
  int tkn = blockIdx.x * blockDim.x + threadIdx.x;
  if (tkn >= T_TOK) return;
  #pragma unroll
  for (int k = 0; k < 2; ++k) {
    int e = tok_e[2 * tkn + k];
    int p = offs[e] + atomicAdd(&cursor[e], 1);
    btok[p] = tkn;
    bw[p] = tok_w[2 * tkn + k];
    tokpos[2 * tkn + k] = p;
  }
}

__global__ void combine_kernel(float* __restrict__ out, const float* __restrict__ rout,
                               const int* __restrict__ tokpos) {
  int tkn = blockIdx.x, c = threadIdx.x;
  int p0 = tokpos[2 * tkn], p1 = tokpos[2 * tkn + 1];
  f32x4* o = (f32x4*)out + (long)tkn * 256;
  const f32x4* a = (const f32x4*)rout + (long)p0 * 256;
  const f32x4* b = (const f32x4*)rout + (long)p1 * 256;
  o[c] = o[c] + a[c] + b[c];
}

// ---------------------------------------------------------------- grouped GEMM1
// Flat grid over real tiles. 256x256, BK=32, 8 waves, 2-phase (r7-proven).
// A rows resolved ONCE per thread via btok (gather fused; gload_lds global
// source is per-lane, m173). C = gelu(A @ B^T + bias) bf16. K=1024, N=4096.
__global__ __launch_bounds__(512)
void moe_gemm1(const unsigned short* __restrict__ x_bf,
               const unsigned short* __restrict__ Wsh, const unsigned short* __restrict__ Wrt,
               const float* __restrict__ bsh, const float* __restrict__ brt,
               unsigned short* __restrict__ Csh, unsigned short* __restrict__ Crt,
               const int* __restrict__ btok,
               const int* __restrict__ cnts, const int* __restrict__ offs,
               const int* __restrict__ tt) {
  __shared__ __align__(16) unsigned short lds[2][2][256][32];   // 64 KB
  const int wid = xcd_swizzle(blockIdx.x, G1_GRID);
  const int mt = wid >> 4, nb = wid & 15;
  if (mt >= tt[9]) return;
  int z = 0;
  while (mt >= tt[z + 1]) ++z;
  const int mlocal = mt - tt[z];

  const unsigned short* Bp;
  const float* bias;
  unsigned short* C;
  int mcnt;
  const unsigned short* srcA0;
  const unsigned short* srcA1;
  const int t = threadIdx.x;
  {
    const int r0 = mlocal * 256 + (t >> 2);
    if (z == NEXP) {
      Bp = Wsh; bias = bsh; C = Csh; mcnt = T_TOK;
      srcA0 = x_bf + (long)r0 * H_DIM;
      srcA1 = x_bf + (long)(r0 + 128) * H_DIM;
    } else {
      const int off = offs[z];
      mcnt = cnts[z];
      Bp = Wrt + (long)z * F_DIM * H_DIM;
      bias = brt + z * F_DIM;
      C = Crt + (long)off * F_DIM;
      int g0 = off + r0, g1 = g0 + 128;
      if (g0 > RT - 1) g0 = RT - 1;            // clamped: tail rows epilogue-masked
      if (g1 > RT - 1) g1 = RT - 1;
      srcA0 = x_bf + (long)btok[g0] * H_DIM;
      srcA1 = x_bf + (long)btok[g1] * H_DIM;
    }
  }

  f32x4 acc[8][4] = {};
  const int nk = H_DIM >> 5;   // 32 K-steps
  const int ch = (t & 3) * 8;

  auto stage = [&](int kt, int buf) {
    {
      const unsigned short* ga = srcA0 + kt * 32 + ch;
      unsigned short* la = &lds[buf][0][0][0] + t * 8;
      __builtin_amdgcn_global_load_lds((const __attribute__((address_space(1))) unsigned int*)ga,
                                       (__attribute__((address_space(3))) unsigned int*)la, 16, 0, 0);
    }
    {
      const unsigned short* ga = srcA1 + kt * 32 + ch;
      unsigned short* la = &lds[buf][0][0][0] + 4096 + t * 8;
      __builtin_amdgcn_global_load_lds((const __attribute__((address_space(1))) unsigned int*)ga,
                                       (__attribute__((address_space(3))) unsigned int*)la, 16, 0, 0);
    }
    #pragma unroll
    for (int i = 0; i < 2; ++i) {
      const int row = i * 128 + (t >> 2);
      const unsigned short* gb = Bp + (long)(nb * 256 + row) * H_DIM + kt * 32 + ch;
      unsigned short* lb = &lds[buf][1][0][0] + i * 4096 + t * 8;
      __builtin_amdgcn_global_load_lds((const __attribute__((address_space(1))) unsigned int*)gb,
                                       (__attribute__((address_space(3))) unsigned int*)lb, 16, 0, 0);
    }
  };

  const int l = t & 63;
  const int w = t >> 6;                       // 8 waves: 2M x 4N
  const int wr = (w >> 2) * 128, wc = (w & 3) * 64;
  const int lr = l & 15, lk = (l >> 4) * 8;

  auto compute = [&](int buf) {
    bf16x8 a[8], b[4];
    #pragma unroll
    for (int m = 0; m < 8; ++m) a[m] = *(const bf16x8*)&lds[buf][0][wr + m * 16 + lr][lk];
    #pragma unroll
    for (int n = 0; n < 4; ++n) b[n] = *(const bf16x8*)&lds[buf][1][wc + n * 16 + lr][lk];
    #pragma unroll
    for (int m = 0; m < 8; ++m)
      #pragma unroll
      for (int n = 0; n < 4; ++n)
        acc[m][n] = __builtin_amdgcn_mfma_f32_16x16x32_bf16(a[m], b[n], acc[m][n], 0, 0, 0);
  };

  stage(0, 0);
  asm volatile("s_waitcnt vmcnt(0)" ::: "memory");
  __syncthreads();
  for (int kt = 0; kt < nk - 1; ++kt) {
    const int cur = kt & 1;
    stage(kt + 1, cur ^ 1);
    compute(cur);
    asm volatile("s_waitcnt vmcnt(0)" ::: "memory");
    __syncthreads();
  }
  compute((nk - 1) & 1);

  // epilogue: C/D layout col=lane&15, row=(lane>>4)*4+j (m89-verified)
  #pragma unroll
  for (int m = 0; m < 8; ++m) {
    #pragma unroll
    for (int n = 0; n < 4; ++n) {
      const int col = nb * 256 + wc + n * 16 + lr;
      const float bc = bias[col];
      #pragma unroll
      for (int j = 0; j < 4; ++j) {
        const int lrow = mlocal * 256 + wr + m * 16 + (l >> 4) * 4 + j;
        if (lrow >= mcnt) continue;
        float v = acc[m][n][j] + bc;
        C[(long)lrow * F_DIM + col] = f2bf(gelu_exact(v));
      }
    }
  }
}

// ---------------------------------------------------------------- grouped GEMM2
// Flat grid. 128x128, BK=32, **8 waves (512 thr, 2Mx4N, acc[4][2])**, 2-phase.
// C = (A @ B^T + bias)[*rowscale] f32. K=4096, N=1024, NB=8.
__global__ __launch_bounds__(512)
void moe_gemm2(const unsigned short* __restrict__ hbuf,
               const unsigned short* __restrict__ Wsh, const unsigned short* __restrict__ Wrt,
               const float* __restrict__ bsh, const float* __restrict__ brt,
               float* __restrict__ out, float* __restrict__ rout,
               const float* __restrict__ bwgt,
               const int* __restrict__ cnts, const int* __restrict__ offs,
               const int* __restrict__ tt) {
  __shared__ __align__(16) unsigned short lds[2][2][128][32];   // 32 KB
  const int wid = xcd_swizzle(blockIdx.x, G2_GRID);
  const int mt = wid >> 3, nb = wid & 7;
  if (mt >= tt[9]) return;
  int z = 0;
  while (mt >= tt[z + 1]) ++z;
  const int mlocal = mt - tt[z];

  const unsigned short* A;
  const unsigned short* Bp;
  const float* bias;
  float* C;
  const float* rs = nullptr;
  int mcnt;
  if (z == NEXP) {
    A = hbuf; Bp = Wsh; bias = bsh; C = out; mcnt = T_TOK;
  } else {
    const int off = offs[z];
    mcnt = cnts[z];
    A = hbuf + ((long)T_TOK + off) * F_DIM;
    Bp = Wrt + (long)z * H_DIM * F_DIM;
    bias = brt + z * H_DIM;
    C = rout + (long)off * H_DIM;
    rs = bwgt + off;
  }

  const int t = threadIdx.x;
  f32x4 acc[4][2] = {};
  const int nk = F_DIM >> 5;   // 128 K-steps

  // staging: 512 threads cover 128x32 in one shot (row = t>>2, 16B chunk t&3)
  auto stage = [&](int kt, int buf) {
    const int row = t >> 2;
    const int ch = (t & 3) * 8;
    const unsigned short* ga = A + (long)(mlocal * 128 + row) * F_DIM + kt * 32 + ch;
    const unsigned short* gb = Bp + (long)(nb * 128 + row) * F_DIM + kt * 32 + ch;
    unsigned short* la = &lds[buf][0][0][0] + t * 8;
    unsigned short* lb = &lds[buf][1][0][0] + t * 8;
    __builtin_amdgcn_global_load_lds((const __attribute__((address_space(1))) unsigned int*)ga,
                                     (__attribute__((address_space(3))) unsigned int*)la, 16, 0, 0);
    __builtin_amdgcn_global_load_lds((const __attribute__((address_space(1))) unsigned int*)gb,
                                     (__attribute__((address_space(3))) unsigned int*)lb, 16, 0, 0);
  };

  const int l = t & 63;
  const int w = t >> 6;                       // 8 waves: 2M x 4N
  const int wr = (w >> 2) * 64, wc = (w & 3) * 32;
  const int lr = l & 15, lk = (l >> 4) * 8;

  auto compute = [&](int buf) {
    bf16x8 a[4], b[2];
    #pragma unroll
    for (int m = 0; m < 4; ++m) a[m] = *(const bf16x8*)&lds[buf][0][wr + m * 16 + lr][lk];
    #pragma unroll
    for (int n = 0; n < 2; ++n) b[n] = *(const bf16x8*)&lds[buf][1][wc + n * 16 + lr][lk];
    #pragma unroll
    for (int m = 0; m < 4; ++m)
      #pragma unroll
      for (int n = 0; n < 2; ++n)
        acc[m][n] = __builtin_amdgcn_mfma_f32_16x16x32_bf16(a[m], b[n], acc[m][n], 0, 0, 0);
  };

  stage(0, 0);
  asm volatile("s_waitcnt vmcnt(0)" ::: "memory");
  __syncthreads();
  for (int kt = 0; kt < nk - 1; ++kt) {
    const int cur = kt & 1;
    stage(kt + 1, cur ^ 1);
    compute(cur);
    asm volatile("s_waitcnt vmcnt(0)" ::: "memory");
    __syncthreads();
  }
  compute((nk - 1) & 1);

  const bool has_rs = (z != NEXP);
  #pragma unroll
  for (int m = 0; m < 4; ++m) {
    #pragma unroll
    for (int n = 0; n < 2; ++n) {
      const int col = nb * 128 + wc + n * 16 + lr;
      const float bc = bias[col];
      #pragma unroll
      for (int j = 0; j < 4; ++j) {
        const int lrow = mlocal * 128 + wr + m * 16 + (l >> 4) * 4 + j;
        if (lrow >= mcnt) continue;
        float v = acc[m][n][j] + bc;
        if (has_rs) v *= rs[lrow];
        C[(long)lrow * H_DIM + col] = v;
      }
    }
  }
}

// ---------------------------------------------------------------- host

extern "C" void kernel_launch(void* const* d_in, const int* in_sizes, int n_in,
                              void* d_out, int out_size, void* d_ws, size_t ws_size,
                              hipStream_t stream) {
  const float* x   = (const float*)d_in[0];
  const float* gw  = (const float*)d_in[1];
  const float* gb  = (const float*)d_in[2];
  const float* rb  = (const float*)d_in[3];
  const float* sw1 = (const float*)d_in[4];
  const float* sb1 = (const float*)d_in[5];
  const float* sw2 = (const float*)d_in[6];
  const float* sb2 = (const float*)d_in[7];
  const float* ew1 = (const float*)d_in[8];
  const float* eb1 = (const float*)d_in[9];
  const float* ew2 = (const float*)d_in[10];
  const float* eb2 = (const float*)d_in[11];

  char* wsp = (char*)d_ws;
  size_t o = 0;
  auto alloc = [&](size_t b) -> void* {
    void* p = wsp + o;
    o = (o + b + 255) & ~(size_t)255;
    return p;
  };
  unsigned short* x_bf = (unsigned short*)alloc((size_t)T_TOK * H_DIM * 2);
  // w1s|w2s|w1e|w2e contiguous (convert4 writes one flat dst)
  unsigned short* w1s  = (unsigned short*)alloc((size_t)F_DIM * H_DIM * 2);
  unsigned short* w2s  = (unsigned short*)alloc((size_t)H_DIM * F_DIM * 2);
  unsigned short* w1e  = (unsigned short*)alloc((size_t)NEXP * F_DIM * H_DIM * 2);
  unsigned short* w2e  = (unsigned short*)alloc((size_t)NEXP * H_DIM * F_DIM * 2);
  unsigned short* hbuf = (unsigned short*)alloc((size_t)(T_TOK + RT + RPAD) * F_DIM * 2);
  float* rout          = (float*)alloc((size_t)RT * H_DIM * 4);
  int*   tok_e  = (int*)alloc(2 * T_TOK * 4);
  float* tok_w  = (float*)alloc(2 * T_TOK * 4);
  int*   tokpos = (int*)alloc(2 * T_TOK * 4);
  int*   btok   = (int*)alloc(RT * 4);
  float* bw     = (float*)alloc(RT * 4);
  int*   meta   = (int*)alloc(1024);
  int* counts = meta, *cursor = meta + 8, *offs = meta + 16;
  int* t1off = meta + 32, *t2off = meta + 48;
  (void)ws_size; (void)in_sizes; (void)n_in; (void)out_size;

  float* out = (float*)d_out;

  zero_kernel<<<1, 64, 0, stream>>>(meta);
  convert4_kernel<<<4096, 256, 0, stream>>>(sw1, sw2, ew1, ew2, w1s);
  gate_kernel<<<T_TOK, 64, 0, stream>>>(x, gw, gb, rb, x_bf, tok_e, tok_w, counts);
  scan_kernel<<<1, 1, 0, stream>>>(counts, offs, t1off, t2off);
  build_kernel<<<T_TOK / 256, 256, 0, stream>>>(tok_e, tok_w, offs, cursor, btok, bw, tokpos);

  // GEMM1: K=1024, N=4096; gather fused via btok-indexed A staging.
  moe_gemm1<<<G1_GRID, 512, 0, stream>>>(
      x_bf, w1s, w1e, sb1, eb1,
      hbuf, hbuf + (size_t)T_TOK * F_DIM, btok, counts, offs, t1off);

  // GEMM2: K=4096, N=1024; 8-wave 128^2.
  moe_gemm2<<<G2_GRID, 512, 0, stream>>>(
      hbuf, w2s, w2e, sb2, eb2, out, rout, bw, counts, offs, t2off);

  combine_kernel<<<T_TOK, 256, 0, stream>>>(out, rout, tokpos);
}

// Round 13
// 582.682 us; speedup vs baseline: 1.2503x; 1.0777x over previous
//
#include <hip/hip_runtime.h>
#include <hip/hip_bf16.h>
#include <math.h>

// DeepSeekMoE: T=4096, H=1024, F=4096, E=8, top-2 sigmoid routing.
// Round 13: single change vs r12 (627us): gemm1 ported to gemm2's winning
// geometry -- 128^2 tile, BK=32, 512 thr / 8 waves (acc[4][2]), 32KB LDS,
// 3 blocks/CU (more independent barrier domains = better drain hiding, m114).
// Reuses the BM=128 tile table (t2off). gemm2/convert/gate/combine untouched.
// Closed lanes: 8-phase (r4/r6), fused convert (r5/r8-r10), atomic combine (r11).

#define T_TOK 4096
#define H_DIM 1024
#define F_DIM 4096
#define NEXP  8
#define RT    (2 * T_TOK)
#define RPAD  512

// worst-case flat grid sizes (fixed for graph capture); BM=128 tiles: 32 shared
// + max 72 expert M-tiles = 104.
#define GT_TILES 104
#define G1_GRID  (GT_TILES * 32)   // NB1 = F/128 = 32
#define G2_GRID  (GT_TILES * 8)    // NB2 = H/128 = 8

typedef __bf16 bf16_t;
typedef __bf16 bf16x8 __attribute__((ext_vector_type(8)));
typedef float  f32x4  __attribute__((ext_vector_type(4)));
typedef unsigned short u16x8 __attribute__((ext_vector_type(8)));

__device__ __forceinline__ unsigned short f2bf(float f) {
  union { bf16_t b; unsigned short u; } cv;
  cv.b = (bf16_t)f;
  return cv.u;
}

__device__ __forceinline__ float gelu_exact(float v) {
  return 0.5f * v * (1.0f + erff(v * 0.70710678118654752f));
}

// bijective XCD swizzle (m204)
__device__ __forceinline__ int xcd_swizzle(int orig, int nwg) {
  const int q = nwg >> 3, r = nwg & 7;
  const int xcd = orig & 7, idx = orig >> 3;
  return (xcd < r ? xcd * (q + 1) : r * (q + 1) + (xcd - r) * q) + idx;
}

// ---------------------------------------------------------------- small kernels

__global__ void zero_kernel(int* p) {
  if (threadIdx.x < 16) p[threadIdx.x] = 0;
}

// all four weight tensors -> contiguous bf16 dst (w1s|w2s|w1e|w2e)
__global__ void convert4_kernel(const float* __restrict__ s0, const float* __restrict__ s1,
                                const float* __restrict__ s2, const float* __restrict__ s3,
                                unsigned short* __restrict__ dst) {
  const long N0 = (long)F_DIM * H_DIM / 8;
  const long N1 = N0 + (long)H_DIM * F_DIM / 8;
  const long N2 = N1 + (long)NEXP * F_DIM * H_DIM / 8;
  const long NT = N2 + (long)NEXP * H_DIM * F_DIM / 8;
  long i = (long)blockIdx.x * blockDim.x + threadIdx.x;
  const long stride = (long)gridDim.x * blockDim.x;
  for (; i < NT; i += stride) {
    const float* s; long j;
    if (i < N0)      { s = s0; j = i; }
    else if (i < N1) { s = s1; j = i - N0; }
    else if (i < N2) { s = s2; j = i - N1; }
    else             { s = s3; j = i - N2; }
    const f32x4* sp = (const f32x4*)s + j * 2;
    f32x4 v0 = sp[0], v1 = sp[1];
    u16x8 o;
    #pragma unroll
    for (int k = 0; k < 4; ++k) { o[k] = f2bf(v0[k]); o[4 + k] = f2bf(v1[k]); }
    *(u16x8*)(dst + i * 8) = o;
  }
}

// one wave per token: 8 gate scores -> sigmoid -> top2; also emits x in bf16
__global__ void gate_kernel(const float* __restrict__ x, const float* __restrict__ gw,
                            const float* __restrict__ gb, const float* __restrict__ rb,
                            unsigned short* __restrict__ x_bf,
                            int* __restrict__ tok_e, float* __restrict__ tok_w,
                            int* __restrict__ counts) {
  int tkn = blockIdx.x;
  int lane = threadIdx.x;
  float acc[NEXP];
  #pragma unroll
  for (int e = 0; e < NEXP; ++e) acc[e] = 0.f;
  const float* xr = x + (long)tkn * H_DIM;
  unsigned short* xbr = x_bf + (long)tkn * H_DIM;
  for (int k = lane; k < H_DIM; k += 64) {
    float xv = xr[k];
    xbr[k] = f2bf(xv);
    #pragma unroll
    for (int e = 0; e < NEXP; ++e) acc[e] += xv * gw[e * H_DIM + k];
  }
  #pragma unroll
  for (int off = 32; off > 0; off >>= 1) {
    #pragma unroll
    for (int e = 0; e < NEXP; ++e) acc[e] += __shfl_xor(acc[e], off, 64);
  }
  if (lane == 0) {
    float s[NEXP];
    #pragma unroll
    for (int e = 0; e < NEXP; ++e)
      s[e] = 1.f / (1.f + expf(-(acc[e] + gb[e] + rb[e])));
    int e0 = 0;
    #pragma unroll
    for (int e = 1; e < NEXP; ++e) if (s[e] > s[e0]) e0 = e;
    int e1 = (e0 == 0) ? 1 : 0;
    #pragma unroll
    for (int e = 0; e < NEXP; ++e) if (e != e0 && e != e1 && s[e] > s[e1]) e1 = e;
    tok_e[2 * tkn] = e0;  tok_e[2 * tkn + 1] = e1;
    tok_w[2 * tkn] = s[e0]; tok_w[2 * tkn + 1] = s[e1];
    atomicAdd(&counts[e0], 1);
    atomicAdd(&counts[e1], 1);
  }
}

// row offsets + per-group M-tile offset table (BM=128, shared for both GEMMs).
__global__ void scan_kernel(const int* __restrict__ counts, int* __restrict__ offs,
                            int* __restrict__ tt) {
  if (threadIdx.x == 0) {
    int o = 0, a = 0;
    for (int e = 0; e < NEXP; ++e) {
      offs[e] = o;
      tt[e] = a;
      a += (counts[e] + 127) >> 7;
      o += counts[e];
    }
    tt[8] = a;
    tt[9] = a + (T_TOK >> 7);
  }
}

__global__ void build_kernel(const int* __restrict__ tok_e, const float* __restrict__ tok_w,
                             const int* __restrict__ offs, int* __restrict__ cursor,
                             int* __restrict__ btok, float* __restrict__ bw,
                             int* __restrict__ tokpos) {
  int tkn = blockIdx.x * blockDim.x + threadIdx.x;
  if (tkn >= T_TOK) return;
  #pragma unroll
  for (int k = 0; k < 2; ++k) {
    int e = tok_e[2 * tkn + k];
    int p = offs[e] + atomicAdd(&cursor[e], 1);
    btok[p] = tkn;
    bw[p] = tok_w[2 * tkn + k];
    tokpos[2 * tkn + k] = p;
  }
}

__global__ void combine_kernel(float* __restrict__ out, const float* __restrict__ rout,
                               const int* __restrict__ tokpos) {
  int tkn = blockIdx.x, c = threadIdx.x;
  int p0 = tokpos[2 * tkn], p1 = tokpos[2 * tkn + 1];
  f32x4* o = (f32x4*)out + (long)tkn * 256;
  const f32x4* a = (const f32x4*)rout + (long)p0 * 256;
  const f32x4* b = (const f32x4*)rout + (long)p1 * 256;
  o[c] = o[c] + a[c] + b[c];
}

// ---------------------------------------------------------------- grouped GEMM1
// Flat grid. 128x128 tile, BK=32, 512 thr / 8 waves (2Mx4N, acc[4][2]),
// 32KB LDS, 2-phase. A rows resolved once per thread via btok (gather fused).
// C = gelu(A @ B^T + bias) bf16. K=1024, N=4096, NB=32.
__global__ __launch_bounds__(512)
void moe_gemm1(const unsigned short* __restrict__ x_bf,
               const unsigned short* __restrict__ Wsh, const unsigned short* __restrict__ Wrt,
               const float* __restrict__ bsh, const float* __restrict__ brt,
               unsigned short* __restrict__ Csh, unsigned short* __restrict__ Crt,
               const int* __restrict__ btok,
               const int* __restrict__ cnts, const int* __restrict__ offs,
               const int* __restrict__ tt) {
  __shared__ __align__(16) unsigned short lds[2][2][128][32];   // 32 KB
  const int wid = xcd_swizzle(blockIdx.x, G1_GRID);
  const int mt = wid >> 5, nb = wid & 31;
  if (mt >= tt[9]) return;
  int z = 0;
  while (mt >= tt[z + 1]) ++z;
  const int mlocal = mt - tt[z];

  const unsigned short* Bp;
  const float* bias;
  unsigned short* C;
  int mcnt;
  const unsigned short* srcA;
  const int t = threadIdx.x;
  {
    const int r0 = mlocal * 128 + (t >> 2);
    if (z == NEXP) {
      Bp = Wsh; bias = bsh; C = Csh; mcnt = T_TOK;
      srcA = x_bf + (long)r0 * H_DIM;
    } else {
      const int off = offs[z];
      mcnt = cnts[z];
      Bp = Wrt + (long)z * F_DIM * H_DIM;
      bias = brt + z * F_DIM;
      C = Crt + (long)off * F_DIM;
      int g0 = off + r0;
      if (g0 > RT - 1) g0 = RT - 1;            // clamped: tail rows epilogue-masked
      srcA = x_bf + (long)btok[g0] * H_DIM;
    }
  }

  f32x4 acc[4][2] = {};
  const int nk = H_DIM >> 5;   // 32 K-steps
  const int ch = (t & 3) * 8;

  auto stage = [&](int kt, int buf) {
    const int row = t >> 2;
    const unsigned short* ga = srcA + kt * 32 + ch;
    const unsigned short* gb = Bp + (long)(nb * 128 + row) * H_DIM + kt * 32 + ch;
    unsigned short* la = &lds[buf][0][0][0] + t * 8;
    unsigned short* lb = &lds[buf][1][0][0] + t * 8;
    __builtin_amdgcn_global_load_lds((const __attribute__((address_space(1))) unsigned int*)ga,
                                     (__attribute__((address_space(3))) unsigned int*)la, 16, 0, 0);
    __builtin_amdgcn_global_load_lds((const __attribute__((address_space(1))) unsigned int*)gb,
                                     (__attribute__((address_space(3))) unsigned int*)lb, 16, 0, 0);
  };

  const int l = t & 63;
  const int w = t >> 6;                       // 8 waves: 2M x 4N
  const int wr = (w >> 2) * 64, wc = (w & 3) * 32;
  const int lr = l & 15, lk = (l >> 4) * 8;

  auto compute = [&](int buf) {
    bf16x8 a[4], b[2];
    #pragma unroll
    for (int m = 0; m < 4; ++m) a[m] = *(const bf16x8*)&lds[buf][0][wr + m * 16 + lr][lk];
    #pragma unroll
    for (int n = 0; n < 2; ++n) b[n] = *(const bf16x8*)&lds[buf][1][wc + n * 16 + lr][lk];
    #pragma unroll
    for (int m = 0; m < 4; ++m)
      #pragma unroll
      for (int n = 0; n < 2; ++n)
        acc[m][n] = __builtin_amdgcn_mfma_f32_16x16x32_bf16(a[m], b[n], acc[m][n], 0, 0, 0);
  };

  stage(0, 0);
  asm volatile("s_waitcnt vmcnt(0)" ::: "memory");
  __syncthreads();
  for (int kt = 0; kt < nk - 1; ++kt) {
    const int cur = kt & 1;
    stage(kt + 1, cur ^ 1);
    compute(cur);
    asm volatile("s_waitcnt vmcnt(0)" ::: "memory");
    __syncthreads();
  }
  compute((nk - 1) & 1);

  // epilogue: C/D layout col=lane&15, row=(lane>>4)*4+j (m89-verified)
  #pragma unroll
  for (int m = 0; m < 4; ++m) {
    #pragma unroll
    for (int n = 0; n < 2; ++n) {
      const int col = nb * 128 + wc + n * 16 + lr;
      const float bc = bias[col];
      #pragma unroll
      for (int j = 0; j < 4; ++j) {
        const int lrow = mlocal * 128 + wr + m * 16 + (l >> 4) * 4 + j;
        if (lrow >= mcnt) continue;
        float v = acc[m][n][j] + bc;
        C[(long)lrow * F_DIM + col] = f2bf(gelu_exact(v));
      }
    }
  }
}

// ---------------------------------------------------------------- grouped GEMM2
// Flat grid. 128x128, BK=32, 8 waves (512 thr, 2Mx4N, acc[4][2]), 2-phase.
// C = (A @ B^T + bias)[*rowscale] f32. K=4096, N=1024, NB=8. (r12-proven.)
__global__ __launch_bounds__(512)
void moe_gemm2(const unsigned short* __restrict__ hbuf,
               const unsigned short* __restrict__ Wsh, const unsigned short* __restrict__ Wrt,
               const float* __restrict__ bsh, const float* __restrict__ brt,
               float* __restrict__ out, float* __restrict__ rout,
               const float* __restrict__ bwgt,
               const int* __restrict__ cnts, const int* __restrict__ offs,
               const int* __restrict__ tt) {
  __shared__ __align__(16) unsigned short lds[2][2][128][32];   // 32 KB
  const int wid = xcd_swizzle(blockIdx.x, G2_GRID);
  const int mt = wid >> 3, nb = wid & 7;
  if (mt >= tt[9]) return;
  int z = 0;
  while (mt >= tt[z + 1]) ++z;
  const int mlocal = mt - tt[z];

  const unsigned short* A;
  const unsigned short* Bp;
  const float* bias;
  float* C;
  const float* rs = nullptr;
  int mcnt;
  if (z == NEXP) {
    A = hbuf; Bp = Wsh; bias = bsh; C = out; mcnt = T_TOK;
  } else {
    const int off = offs[z];
    mcnt = cnts[z];
    A = hbuf + ((long)T_TOK + off) * F_DIM;
    Bp = Wrt + (long)z * H_DIM * F_DIM;
    bias = brt + z * H_DIM;
    C = rout + (long)off * H_DIM;
    rs = bwgt + off;
  }

  const int t = threadIdx.x;
  f32x4 acc[4][2] = {};
  const int nk = F_DIM >> 5;   // 128 K-steps

  auto stage = [&](int kt, int buf) {
    const int row = t >> 2;
    const int ch = (t & 3) * 8;
    const unsigned short* ga = A + (long)(mlocal * 128 + row) * F_DIM + kt * 32 + ch;
    const unsigned short* gb = Bp + (long)(nb * 128 + row) * F_DIM + kt * 32 + ch;
    unsigned short* la = &lds[buf][0][0][0] + t * 8;
    unsigned short* lb = &lds[buf][1][0][0] + t * 8;
    __builtin_amdgcn_global_load_lds((const __attribute__((address_space(1))) unsigned int*)ga,
                                     (__attribute__((address_space(3))) unsigned int*)la, 16, 0, 0);
    __builtin_amdgcn_global_load_lds((const __attribute__((address_space(1))) unsigned int*)gb,
                                     (__attribute__((address_space(3))) unsigned int*)lb, 16, 0, 0);
  };

  const int l = t & 63;
  const int w = t >> 6;                       // 8 waves: 2M x 4N
  const int wr = (w >> 2) * 64, wc = (w & 3) * 32;
  const int lr = l & 15, lk = (l >> 4) * 8;

  auto compute = [&](int buf) {
    bf16x8 a[4], b[2];
    #pragma unroll
    for (int m = 0; m < 4; ++m) a[m] = *(const bf16x8*)&lds[buf][0][wr + m * 16 + lr][lk];
    #pragma unroll
    for (int n = 0; n < 2; ++n) b[n] = *(const bf16x8*)&lds[buf][1][wc + n * 16 + lr][lk];
    #pragma unroll
    for (int m = 0; m < 4; ++m)
      #pragma unroll
      for (int n = 0; n < 2; ++n)
        acc[m][n] = __builtin_amdgcn_mfma_f32_16x16x32_bf16(a[m], b[n], acc[m][n], 0, 0, 0);
  };

  stage(0, 0);
  asm volatile("s_waitcnt vmcnt(0)" ::: "memory");
  __syncthreads();
  for (int kt = 0; kt < nk - 1; ++kt) {
    const int cur = kt & 1;
    stage(kt + 1, cur ^ 1);
    compute(cur);
    asm volatile("s_waitcnt vmcnt(0)" ::: "memory");
    __syncthreads();
  }
  compute((nk - 1) & 1);

  const bool has_rs = (z != NEXP);
  #pragma unroll
  for (int m = 0; m < 4; ++m) {
    #pragma unroll
    for (int n = 0; n < 2; ++n) {
      const int col = nb * 128 + wc + n * 16 + lr;
      const float bc = bias[col];
      #pragma unroll
      for (int j = 0; j < 4; ++j) {
        const int lrow = mlocal * 128 + wr + m * 16 + (l >> 4) * 4 + j;
        if (lrow >= mcnt) continue;
        float v = acc[m][n][j] + bc;
        if (has_rs) v *= rs[lrow];
        C[(long)lrow * H_DIM + col] = v;
      }
    }
  }
}

// ---------------------------------------------------------------- host

extern "C" void kernel_launch(void* const* d_in, const int* in_sizes, int n_in,
                              void* d_out, int out_size, void* d_ws, size_t ws_size,
                              hipStream_t stream) {
  const float* x   = (const float*)d_in[0];
  const float* gw  = (const float*)d_in[1];
  const float* gb  = (const float*)d_in[2];
  const float* rb  = (const float*)d_in[3];
  const float* sw1 = (const float*)d_in[4];
  const float* sb1 = (const float*)d_in[5];
  const float* sw2 = (const float*)d_in[6];
  const float* sb2 = (const float*)d_in[7];
  const float* ew1 = (const float*)d_in[8];
  const float* eb1 = (const float*)d_in[9];
  const float* ew2 = (const float*)d_in[10];
  const float* eb2 = (const float*)d_in[11];

  char* wsp = (char*)d_ws;
  size_t o = 0;
  auto alloc = [&](size_t b) -> void* {
    void* p = wsp + o;
    o = (o + b + 255) & ~(size_t)255;
    return p;
  };
  unsigned short* x_bf = (unsigned short*)alloc((size_t)T_TOK * H_DIM * 2);
  // w1s|w2s|w1e|w2e contiguous (convert4 writes one flat dst)
  unsigned short* w1s  = (unsigned short*)alloc((size_t)F_DIM * H_DIM * 2);
  unsigned short* w2s  = (unsigned short*)alloc((size_t)H_DIM * F_DIM * 2);
  unsigned short* w1e  = (unsigned short*)alloc((size_t)NEXP * F_DIM * H_DIM * 2);
  unsigned short* w2e  = (unsigned short*)alloc((size_t)NEXP * H_DIM * F_DIM * 2);
  unsigned short* hbuf = (unsigned short*)alloc((size_t)(T_TOK + RT + RPAD) * F_DIM * 2);
  float* rout          = (float*)alloc((size_t)RT * H_DIM * 4);
  int*   tok_e  = (int*)alloc(2 * T_TOK * 4);
  float* tok_w  = (float*)alloc(2 * T_TOK * 4);
  int*   tokpos = (int*)alloc(2 * T_TOK * 4);
  int*   btok   = (int*)alloc(RT * 4);
  float* bw     = (float*)alloc(RT * 4);
  int*   meta   = (int*)alloc(1024);
  int* counts = meta, *cursor = meta + 8, *offs = meta + 16;
  int* ttof = meta + 32;
  (void)ws_size; (void)in_sizes; (void)n_in; (void)out_size;

  float* out = (float*)d_out;

  zero_kernel<<<1, 64, 0, stream>>>(meta);
  convert4_kernel<<<4096, 256, 0, stream>>>(sw1, sw2, ew1, ew2, w1s);
  gate_kernel<<<T_TOK, 64, 0, stream>>>(x, gw, gb, rb, x_bf, tok_e, tok_w, counts);
  scan_kernel<<<1, 1, 0, stream>>>(counts, offs, ttof);
  build_kernel<<<T_TOK / 256, 256, 0, stream>>>(tok_e, tok_w, offs, cursor, btok, bw, tokpos);

  // GEMM1: K=1024, N=4096; 128^2 8-wave; gather fused via btok-indexed A staging.
  moe_gemm1<<<G1_GRID, 512, 0, stream>>>(
      x_bf, w1s, w1e, sb1, eb1,
      hbuf, hbuf + (size_t)T_TOK * F_DIM, btok, counts, offs, ttof);

  // GEMM2: K=4096, N=1024; 128^2 8-wave (r12-proven).
  moe_gemm2<<<G2_GRID, 512, 0, stream>>>(
      hbuf, w2s, w2e, sb2, eb2, out, rout, bw, counts, offs, ttof);

  combine_kernel<<<T_TOK, 256, 0, stream>>>(out, rout, tokpos);
}